// Round 19
// baseline (359.918 us; speedup 1.0000x reference)
//
#include <hip/hip_runtime.h>
#include <hip/hip_bf16.h>

#define SLEN 4096
#define DH 768
#define NHEAD 12
#define DA 64

using short8 = __attribute__((ext_vector_type(8))) short;
using f32x4  = __attribute__((ext_vector_type(4))) float;
typedef unsigned uv2 __attribute__((ext_vector_type(2)));

static __device__ __forceinline__ unsigned short f2b(float f) {
    union { __hip_bfloat16 h; unsigned short u; } c;
    c.h = __float2bfloat16(f);
    return c.u;
}

static __device__ __forceinline__ unsigned pkbf(float a, float b) {
    __hip_bfloat162 h = __float22bfloat162_rn(float2{a, b});
    union { __hip_bfloat162 h; unsigned u; } c; c.h = h; return c.u;
}

// native 2^x — single v_exp_f32, no libcall fallback
static __device__ __forceinline__ float fexp2(float x) {
    float r; asm("v_exp_f32 %0, %1" : "=v"(r) : "v"(x)); return r;
}

// {a,b} -> a'={a.lo,b.lo}, b'={a.hi,b.hi}  (swap across lane^32)
static __device__ __forceinline__ void swap32(unsigned& a, unsigned& b, int g1) {
#if __has_builtin(__builtin_amdgcn_permlane32_swap)
    uv2 r = __builtin_amdgcn_permlane32_swap(a, b, false, false);
    a = r.x; b = r.y;
#else
    unsigned own = g1 ? b : a, send = g1 ? a : b;
    unsigned recv = __shfl_xor(send, 32);
    unsigned nlo = g1 ? recv : own;
    unsigned nhi = g1 ? own : recv;
    a = nlo; b = nhi;
#endif
}

// {a,b} -> a'={a.q0,b.q0,a.q2,b.q2}, b'={a.q1,b.q1,a.q3,b.q3}  (swap across lane^16)
static __device__ __forceinline__ void swap16(unsigned& a, unsigned& b, int g0) {
#if __has_builtin(__builtin_amdgcn_permlane16_swap)
    uv2 r = __builtin_amdgcn_permlane16_swap(a, b, false, false);
    a = r.x; b = r.y;
#else
    unsigned own = g0 ? b : a, send = g0 ? a : b;
    unsigned recv = __shfl_xor(send, 16);
    unsigned nlo = g0 ? recv : own;
    unsigned nhi = g0 ? own : recv;
    a = nlo; b = nhi;
#endif
}

#define GLD_LDS16(gp, lp) __builtin_amdgcn_global_load_lds( \
    (const __attribute__((address_space(1))) unsigned int*)(gp), \
    (__attribute__((address_space(3))) unsigned int*)(lp), 16, 0, 0)

#define CSCALE 0.18033688011f   // 0.125 * log2(e)
#define BIASSTRIDE 4352

// ------- merged: 4x weight transpose+cvt (z<4), mask compaction scan (z==4, blocks 0..1) -------
__global__ __launch_bounds__(256) void wtrans4(const float* __restrict__ w_v, const float* __restrict__ w_k,
                                               const float* __restrict__ w_q, const float* __restrict__ w_o,
                                               unsigned short* __restrict__ WtV, unsigned short* __restrict__ WtK,
                                               unsigned short* __restrict__ WtQ, unsigned short* __restrict__ WtO,
                                               const int* __restrict__ mask, int* __restrict__ idx,
                                               float* __restrict__ biasC, int* __restrict__ nktArr) {
    const int z = blockIdx.y;
    const int t = threadIdx.x;
    if (z == 4) {
        if (blockIdx.x >= 2) return;
        __shared__ int psum[256];
        const int b = blockIdx.x;
        const int s0 = t * 16;
        const int* mb = mask + b * SLEN;
        int keep[16]; int cnt = 0;
#pragma unroll
        for (int j = 0; j < 16; ++j) { keep[j] = (mb[s0 + j] == 0); cnt += keep[j]; }
        psum[t] = cnt;
        __syncthreads();
        for (int off = 1; off < 256; off <<= 1) {
            int v = psum[t];
            int u = (t >= off) ? psum[t - off] : 0;
            __syncthreads();
            psum[t] = v + u;
            __syncthreads();
        }
        int excl = psum[t] - cnt;
        int total = psum[255];
        int* ib = idx + b * SLEN;
#pragma unroll
        for (int j = 0; j < 16; ++j)
            if (keep[j]) ib[excl++] = s0 + j;
        for (int j = total + t; j < SLEN; j += 256) ib[j] = 0;
        int nkt = (total + 63) >> 6;
        if (nkt < 2) nkt = 2;
        if (t == 0) { nktArr[b] = nkt; nktArr[2 + b] = total; }
        float* bb = biasC + b * BIASSTRIDE;
        for (int j = t; j < BIASSTRIDE; j += 256) bb[j] = (j < total) ? 0.f : -1.442695041e9f;
        return;
    }
    const float* W = (z == 0) ? w_v : (z == 1) ? w_k : (z == 2) ? w_q : w_o;
    unsigned short* Wt = (z == 0) ? WtV : (z == 1) ? WtK : (z == 2) ? WtQ : WtO;
    __shared__ float tile[64][65];
    const int tk = blockIdx.x / 12, tn = blockIdx.x % 12;
    const int k0 = tk * 64, n0 = tn * 64;
#pragma unroll
    for (int i = 0; i < 4; ++i) {
        int uid = t + 256 * i;
        int r = uid >> 4, c = (uid & 15) * 4;
        float4 v4 = *reinterpret_cast<const float4*>(W + (size_t)(k0 + r) * DH + n0 + c);
        tile[r][c] = v4.x; tile[r][c + 1] = v4.y; tile[r][c + 2] = v4.z; tile[r][c + 3] = v4.w;
    }
    __syncthreads();
#pragma unroll
    for (int i = 0; i < 2; ++i) {
        int uid = t + 256 * i;
        int n = uid >> 3, c = (uid & 7) * 8;
        union { unsigned short us[8]; uint4 u; } pk;
#pragma unroll
        for (int j = 0; j < 8; ++j) pk.us[j] = f2b(tile[c + j][n]);
        *reinterpret_cast<uint4*>(Wt + (size_t)(n0 + n) * DH + k0 + c) = pk.u;
    }
}

// ---- fused QKV projection + compaction, m97 geometry: BM=128, BN=128, BK=32, ring-2 ----
__global__ __launch_bounds__(256, 3) void proj3(const float* __restrict__ vin, const float* __restrict__ kin,
                                                const float* __restrict__ qin,
                                                const unsigned short* __restrict__ WtV,
                                                const unsigned short* __restrict__ WtK,
                                                const unsigned short* __restrict__ WtQ,
                                                unsigned short* __restrict__ VhTc,
                                                unsigned short* __restrict__ Khc,
                                                unsigned short* __restrict__ Qh,
                                                const int* __restrict__ idx,
                                                const int* __restrict__ nktArr) {
    __shared__ __align__(16) char smem[49152];
    const int t = threadIdx.x;
    const int w = t >> 6, lane = t & 63, lr = lane & 15, lg = lane >> 4;
    const int zz = blockIdx.y;
    const int z = zz / 6, panel = zz % 6;
    const float* X = (z == 0) ? vin : (z == 1) ? kin : qin;
    const unsigned short* Wt = (z == 0) ? WtV : (z == 1) ? WtK : WtQ;
    const int b = blockIdx.x >> 5;
    const int r128 = (blockIdx.x & 31) * 128;
    const bool gather = (z != 2);
    if (gather && r128 >= nktArr[b] * 64) return;
    const int n0 = panel * 128;

    const float* ap[4];
#pragma unroll
    for (int g = 0; g < 4; ++g) {
        int row = w * 32 + g * 8 + (lane >> 3);
        int grow = b * SLEN + (gather ? idx[b * SLEN + r128 + row] : (r128 + row));
        int cj = (lane & 7) ^ (row & 7);
        ap[g] = X + (size_t)grow * DH + cj * 4;
    }
    const unsigned short* bp2[2];
#pragma unroll
    for (int g = 0; g < 2; ++g) {
        int n = w * 32 + g * 16 + (lane >> 2);
        int cj = (lane & 3) ^ (n & 3);
        bp2[g] = Wt + (size_t)(n0 + n) * DH + cj * 8;
    }

    const int arow = w * 32 + lr;
    const int lr7 = lr & 7, lr3 = lr & 3;

    f32x4 acc[2][8] = {};

#define STAGE(PAR) do {                                                              \
        char* ab_ = smem + (PAR) * 16384 + w * 4096;                                 \
        char* bb_ = smem + 32768 + (PAR) * 8192 + w * 2048;                          \
        GLD_LDS16(ap[0], ab_);         GLD_LDS16(ap[1], ab_ + 1024);                 \
        GLD_LDS16(ap[2], ab_ + 2048);  GLD_LDS16(ap[3], ab_ + 3072);                 \
        GLD_LDS16(bp2[0], bb_);        GLD_LDS16(bp2[1], bb_ + 1024);                \
        ap[0] += 32; ap[1] += 32; ap[2] += 32; ap[3] += 32;                          \
        bp2[0] += 32; bp2[1] += 32;                                                  \
    } while (0)

    STAGE(0);
    __syncthreads();

    for (int kt = 0; kt < 24; ++kt) {
        const int par = kt & 1;
        if (kt < 23) STAGE(par ^ 1);
        const char* bufA = smem + par * 16384;
        const char* bufB = smem + 32768 + par * 8192;
        short8 af[2];
#pragma unroll
        for (int mi = 0; mi < 2; ++mi) {
            int r = arow + mi * 16;
            f32x4 alo = *reinterpret_cast<const f32x4*>(bufA + r * 128 + ((2 * lg) ^ lr7) * 16);
            f32x4 ahi = *reinterpret_cast<const f32x4*>(bufA + r * 128 + ((2 * lg + 1) ^ lr7) * 16);
            union { unsigned u[4]; short8 s; } pk;
            pk.u[0] = pkbf(alo[0], alo[1]);
            pk.u[1] = pkbf(alo[2], alo[3]);
            pk.u[2] = pkbf(ahi[0], ahi[1]);
            pk.u[3] = pkbf(ahi[2], ahi[3]);
            af[mi] = pk.s;
        }
        __builtin_amdgcn_s_setprio(1);
#pragma unroll
        for (int ni = 0; ni < 8; ++ni) {
            int n = ni * 16 + lr;
            short8 bf = *reinterpret_cast<const short8*>(bufB + n * 64 + (lg ^ lr3) * 16);
            acc[0][ni] = __builtin_amdgcn_mfma_f32_16x16x32_bf16(af[0], bf, acc[0][ni], 0, 0, 0);
            acc[1][ni] = __builtin_amdgcn_mfma_f32_16x16x32_bf16(af[1], bf, acc[1][ni], 0, 0, 0);
        }
        __builtin_amdgcn_s_setprio(0);
        __syncthreads();
    }
#undef STAGE

    if (z == 0) {
        unsigned short (*tile)[136] = reinterpret_cast<unsigned short(*)[136]>(smem);
#pragma unroll
        for (int mi = 0; mi < 2; ++mi)
#pragma unroll
            for (int ni = 0; ni < 8; ++ni) {
                int n = ni * 16 + lr;
                int j = w * 32 + mi * 16 + lg * 4;
                *reinterpret_cast<unsigned*>(&tile[n][j])     = pkbf(acc[mi][ni][0], acc[mi][ni][1]);
                *reinterpret_cast<unsigned*>(&tile[n][j + 2]) = pkbf(acc[mi][ni][2], acc[mi][ni][3]);
            }
        __syncthreads();
        int n = t >> 1, jc = (t & 1) * 64;
        unsigned short* dst = VhTc +
            ((size_t)(b * NHEAD + 2 * panel + (n >> 6)) * DA + (n & 63)) * SLEN + r128 + jc;
#pragma unroll
        for (int c = 0; c < 8; ++c)
            *reinterpret_cast<uint4*>(dst + c * 8) = *reinterpret_cast<const uint4*>(&tile[n][jc + c * 8]);
    } else {
        unsigned short* Y = (z == 1) ? Khc : Qh;
        const float scale = (z == 2) ? CSCALE : 1.0f;
#pragma unroll
        for (int mi = 0; mi < 2; ++mi)
#pragma unroll
            for (int ni = 0; ni < 8; ++ni) {
                int n = n0 + ni * 16 + lr;
                int h = n >> 6, d = n & 63;
#pragma unroll
                for (int r = 0; r < 4; ++r) {
                    int s = r128 + w * 32 + mi * 16 + lg * 4 + r;
                    Y[(size_t)((b * NHEAD + h) * SLEN + s) * DA + d] = f2b(acc[mi][ni][r] * scale);
                }
            }
    }
}

// ---------------- flash attention: QBLK=128, K direct-to-registers (dbuf), V in ring-3 LDS ----------------
// K fragments are wave-private and swizzle-free -> load global->VGPR (L2-resident via XCD swizzle),
// halving ds_read traffic. KLOAD issued BEFORE the same body's V global_load_lds, so waiting on K
// never drains the V prefetch. 6x-unrolled bodies align the 3-V-buffer x 2-K-regset cycle (all static).
__global__ __launch_bounds__(256, 3) void attn_kernel(const unsigned short* __restrict__ Qh,
                                                      const unsigned short* __restrict__ Kh,
                                                      const unsigned short* __restrict__ VhT,
                                                      const float* __restrict__ biasC,
                                                      const int* __restrict__ nktArr,
                                                      unsigned short* __restrict__ AT) {
    __shared__ __align__(16) char smem[24576];   // 3 x V 8KB; epilogue reuse
    const int t = threadIdx.x;
    const int w = t >> 6, lane = t & 63, lr = lane & 15, lg = lane >> 4;
    const int g0 = (lane >> 4) & 1, g1 = (lane >> 5) & 1;
    const int lr7 = lr & 7;

    const int i = blockIdx.x;          // 0..767
    const int bh = (i & 7) * 3 + ((i >> 3) >> 5);
    const int qb = (i >> 3) & 31;
    const int b = bh / NHEAD;
    const int q0 = qb * 128;
    const size_t base = (size_t)bh * SLEN * DA;
    const int wq0 = q0 + w * 32;
    const int nkt = nktArr[b];
    const int padStart = nktArr[2 + b] >> 6;

    short8 qf[2][2];
#pragma unroll
    for (int mi = 0; mi < 2; ++mi)
#pragma unroll
        for (int ks = 0; ks < 2; ++ks)
            qf[mi][ks] = *reinterpret_cast<const short8*>(
                Qh + base + (size_t)(wq0 + mi * 16 + lr) * DA + ks * 32 + lg * 8);

    // V staging source (pre-swizzle-free: V rows d, 16B chunks) — same per-lane map as R18
    const int uid0 = (w << 6) | lane;
    const int r0 = uid0 >> 3;
    const int sc0 = ((uid0 & 7) ^ (r0 & 7)) * 8;
    const unsigned short* vp = VhT + ((size_t)bh * DA + r0) * SLEN + sc0;
    // K direct-load pointer: lane reads row (ni*16+lr), bytes ks*64 + lg*16 — static imm offsets
    const unsigned short* kq = Kh + base + (size_t)lr * DA + lg * 8;
    const float* biasB = biasC + b * BIASSTRIDE + lg * 4;

    const int a0 = lr * 128 + ((lg) ^ lr7) * 16;
    const int a1 = lr * 128 + ((4 + lg) ^ lr7) * 16;

    f32x4 st[2][4];
    f32x4 oacc[2][4] = {};
    f32x4 oacc_l[2] = {};
    f32x4 bias_c[4] = {};
    short8 pa[2][2];
    short8 kfA[4][2], kfB[4][2];       // double-buffered K fragment sets (tile T -> set T&1)
    union { unsigned u[4]; short8 s; } ones;
    ones.u[0] = 0x3F803F80u; ones.u[1] = 0x3F803F80u; ones.u[2] = 0x3F803F80u; ones.u[3] = 0x3F803F80u;

#define STAGE_V(CB) do {                                                 \
        GLD_LDS16(vp,              smem + (CB) + w * 1024);              \
        GLD_LDS16(vp + 32 * SLEN,  smem + (CB) + (4 + w) * 1024);        \
        vp += 64;                                                        \
    } while (0)

#define KLOAD(SET) do {                                                          \
        _Pragma("unroll") for (int ni = 0; ni < 4; ++ni) {                       \
            SET[ni][0] = *reinterpret_cast<const short8*>(kq + ni * 1024);       \
            SET[ni][1] = *reinterpret_cast<const short8*>(kq + ni * 1024 + 32);  \
        }                                                                        \
        kq += 64 * DA;                                                           \
    } while (0)

#define BIASCOND(TT) do {                                                        \
        if ((TT) >= padStart) {                                                  \
            const float* bpp_ = biasB + (TT) * 64;                               \
            _Pragma("unroll") for (int ni = 0; ni < 4; ++ni)                     \
                bias_c[ni] = *reinterpret_cast<const f32x4*>(bpp_ + ni * 16);    \
        }                                                                        \
    } while (0)

#define QKT(SET) do {                                                                          \
        _Pragma("unroll") for (int ni = 0; ni < 4; ++ni) {                                     \
            st[0][ni] = __builtin_amdgcn_mfma_f32_16x16x32_bf16(SET[ni][1], qf[0][1],          \
                        __builtin_amdgcn_mfma_f32_16x16x32_bf16(SET[ni][0], qf[0][0], bias_c[ni], 0, 0, 0), 0, 0, 0); \
            st[1][ni] = __builtin_amdgcn_mfma_f32_16x16x32_bf16(SET[ni][1], qf[1][1],          \
                        __builtin_amdgcn_mfma_f32_16x16x32_bf16(SET[ni][0], qf[1][0], bias_c[ni], 0, 0, 0), 0, 0, 0); \
        }                                                                                      \
    } while (0)

#define PV(CB) do {                                                                                  \
        _Pragma("unroll") for (int ni = 0; ni < 4; ++ni) {                                           \
            short8 vf0 = *reinterpret_cast<const short8*>(smem + (CB) + ni * 2048 + a0);             \
            short8 vf1 = *reinterpret_cast<const short8*>(smem + (CB) + ni * 2048 + a1);             \
            oacc[0][ni] = __builtin_amdgcn_mfma_f32_16x16x32_bf16(vf0, pa[0][0], oacc[0][ni], 0, 0, 0); \
            oacc[0][ni] = __builtin_amdgcn_mfma_f32_16x16x32_bf16(vf1, pa[0][1], oacc[0][ni], 0, 0, 0); \
            oacc[1][ni] = __builtin_amdgcn_mfma_f32_16x16x32_bf16(vf0, pa[1][0], oacc[1][ni], 0, 0, 0); \
            oacc[1][ni] = __builtin_amdgcn_mfma_f32_16x16x32_bf16(vf1, pa[1][1], oacc[1][ni], 0, 0, 0); \
        }                                                                                            \
        oacc_l[0] = __builtin_amdgcn_mfma_f32_16x16x32_bf16(ones.s, pa[0][0], oacc_l[0], 0, 0, 0);   \
        oacc_l[0] = __builtin_amdgcn_mfma_f32_16x16x32_bf16(ones.s, pa[0][1], oacc_l[0], 0, 0, 0);   \
        oacc_l[1] = __builtin_amdgcn_mfma_f32_16x16x32_bf16(ones.s, pa[1][0], oacc_l[1], 0, 0, 0);   \
        oacc_l[1] = __builtin_amdgcn_mfma_f32_16x16x32_bf16(ones.s, pa[1][1], oacc_l[1], 0, 0, 0);   \
    } while (0)

#define SOFTMAX do {                                                                               \
        _Pragma("unroll") for (int mi = 0; mi < 2; ++mi) {                                         \
            unsigned D[8];                                                                         \
            _Pragma("unroll") for (int ni = 0; ni < 4; ++ni) {                                     \
                float p0 = fexp2(st[mi][ni][0]);                                                   \
                float p1 = fexp2(st[mi][ni][1]);                                                   \
                float p2 = fexp2(st[mi][ni][2]);                                                   \
                float p3 = fexp2(st[mi][ni][3]);                                                   \
                D[ni * 2] = pkbf(p0, p1);                                                          \
                D[ni * 2 + 1] = pkbf(p2, p3);                                                      \
            }                                                                                      \
            swap32(D[0], D[2], g1); swap32(D[1], D[3], g1);                                        \
            swap32(D[4], D[6], g1); swap32(D[5], D[7], g1);                                        \
            swap16(D[0], D[2], g0); swap16(D[1], D[3], g0);                                        \
            swap16(D[4], D[6], g0); swap16(D[5], D[7], g0);                                        \
            union { unsigned u[4]; short8 s; } c0, c1;                                             \
            c0.u[0] = D[0]; c0.u[1] = D[1]; c0.u[2] = D[2]; c0.u[3] = D[3];                        \
            c1.u[0] = D[4]; c1.u[1] = D[5]; c1.u[2] = D[6]; c1.u[3] = D[7];                        \
            pa[mi][0] = c0.s; pa[mi][1] = c1.s;                                                    \
        }                                                                                          \
    } while (0)

// BODY(KT): SOFTMAX(kt) | barrier | {V-stage(kt+2); KLOAD(kt+2 -> NXTSET)} | QKT(kt+1 from CURSET) | PV(kt)
#define BODY(KT, CB, NNB, CURSET, NXTSET) do {                           \
        SOFTMAX;                                                         \
        __syncthreads();                                                 \
        if ((KT) < nkt - 2) { STAGE_V(NNB); KLOAD(NXTSET); }             \
        BIASCOND((KT) + 1);                                              \
        __builtin_amdgcn_s_setprio(1);                                   \
        QKT(CURSET);                                                     \
        PV(CB);                                                          \
        __builtin_amdgcn_s_setprio(0);                                   \
    } while (0)

    // prologue: V(0) staged + K(0)->A; sync; V(1) staged + K(1)->B; bias(0); QKT(0 from A)
    STAGE_V(0);
    KLOAD(kfA);
    __syncthreads();
    STAGE_V(8192);
    KLOAD(kfB);
    BIASCOND(0);
    __builtin_amdgcn_s_setprio(1);
    QKT(kfA);
    __builtin_amdgcn_s_setprio(0);

    int kt = 0;
    while (kt + 6 <= nkt - 1) {        // kt stays a multiple of 6 -> all parities static
        BODY(kt + 0, 0,     16384, kfB, kfA);
        BODY(kt + 1, 8192,  0,     kfA, kfB);
        BODY(kt + 2, 16384, 8192,  kfB, kfA);
        BODY(kt + 3, 0,     16384, kfA, kfB);
        BODY(kt + 4, 8192,  0,     kfB, kfA);
        BODY(kt + 5, 16384, 8192,  kfA, kfB);
        kt += 6;
    }
    const int rem = (nkt - 1) - kt;    // 0..5 remaining loop-bodies
    if (rem >= 1) BODY(kt + 0, 0,     16384, kfB, kfA);
    if (rem >= 2) BODY(kt + 1, 8192,  0,     kfA, kfB);
    if (rem >= 3) BODY(kt + 2, 16384, 8192,  kfB, kfA);
    if (rem >= 4) BODY(kt + 3, 0,     16384, kfA, kfB);
    if (rem >= 5) BODY(kt + 4, 8192,  0,     kfB, kfA);
    // final tile (nkt-1), V in buffer ((nkt-1) % 3)
    SOFTMAX;
    {
        const int cbF = ((nkt - 1) % 3) * 8192;
        __builtin_amdgcn_s_setprio(1);
        PV(cbF);
        __builtin_amdgcn_s_setprio(0);
    }

#undef BODY
#undef SOFTMAX
#undef PV
#undef QKT
#undef BIASCOND
#undef KLOAD
#undef STAGE_V

    {
        __syncthreads();
        float inv[2];
        inv[0] = 1.0f / oacc_l[0][0];
        inv[1] = 1.0f / oacc_l[1][0];
        unsigned* Obw = reinterpret_cast<unsigned*>(smem) + w * (32 * 36);
#pragma unroll
        for (int mi = 0; mi < 2; ++mi)
#pragma unroll
            for (int ni = 0; ni < 4; ++ni) {
                uint2 pr;
                pr.x = pkbf(oacc[mi][ni][0] * inv[mi], oacc[mi][ni][1] * inv[mi]);
                pr.y = pkbf(oacc[mi][ni][2] * inv[mi], oacc[mi][ni][3] * inv[mi]);
                *reinterpret_cast<uint2*>(&Obw[(mi * 16 + lr) * 36 + ni * 8 + lg * 2]) = pr;
            }
        __syncthreads();
        int row = lane >> 1, half = lane & 1;
        int qg = q0 + w * 32 + row;
        unsigned short* dst = AT + (size_t)(b * SLEN + qg) * DH + (bh % NHEAD) * DA + half * 32;
#pragma unroll
        for (int c = 0; c < 4; ++c) {
            uint4 v = *reinterpret_cast<const uint4*>(&Obw[row * 36 + half * 16 + c * 4]);
            *reinterpret_cast<uint4*>(dst + c * 8) = v;
        }
    }
}

// ---- output projection, m97 geometry: BM=128, BN=64, BK=64, ring-2, 1 barrier/K-step ----
__global__ __launch_bounds__(256, 3) void proj_out(const unsigned short* __restrict__ X,
                                                   const unsigned short* __restrict__ Wt,
                                                   const float* __restrict__ bias,
                                                   float* __restrict__ Y) {
    __shared__ __align__(16) char smem[49152];
    const int t = threadIdx.x;
    const int w = t >> 6, lane = t & 63, lr = lane & 15, lg = lane >> 4;
    const int row0 = blockIdx.x * 128;
    const int n0 = blockIdx.y * 64;
    const int lr7 = lr & 7;

    const unsigned short* ap[4];
#pragma unroll
    for (int g = 0; g < 4; ++g) {
        int row = w * 32 + g * 8 + (lane >> 3);
        int cj = (lane & 7) ^ (row & 7);
        ap[g] = X + (size_t)(row0 + row) * DH + cj * 8;
    }
    const unsigned short* bp2[2];
#pragma unroll
    for (int g = 0; g < 2; ++g) {
        int n = w * 16 + g * 8 + (lane >> 3);
        int cj = (lane & 7) ^ (n & 7);
        bp2[g] = Wt + (size_t)(n0 + n) * DH + cj * 8;
    }

    f32x4 acc[2][4] = {};

#define STAGE_O(PAR) do {                                                            \
        char* ab_ = smem + (PAR) * 16384 + w * 4096;                                 \
        char* bb_ = smem + 32768 + (PAR) * 8192 + w * 2048;                          \
        GLD_LDS16(ap[0], ab_);         GLD_LDS16(ap[1], ab_ + 1024);                 \
        GLD_LDS16(ap[2], ab_ + 2048);  GLD_LDS16(ap[3], ab_ + 3072);                 \
        GLD_LDS16(bp2[0], bb_);        GLD_LDS16(bp2[1], bb_ + 1024);                \
        ap[0] += 64; ap[1] += 64; ap[2] += 64; ap[3] += 64;                          \
        bp2[0] += 64; bp2[1] += 64;                                                  \
    } while (0)

    STAGE_O(0);
    __syncthreads();

    for (int kt = 0; kt < 12; ++kt) {
        const int par = kt & 1;
        if (kt < 11) STAGE_O(par ^ 1);
        const char* bufA = smem + par * 16384;
        const char* bufB = smem + 32768 + par * 8192;
        short8 af[2][2], bf[4][2];
#pragma unroll
        for (int mi = 0; mi < 2; ++mi) {
            int r = w * 32 + mi * 16 + lr;
#pragma unroll
            for (int ks = 0; ks < 2; ++ks)
                af[mi][ks] = *reinterpret_cast<const short8*>(bufA + r * 128 + ((ks * 4 + lg) ^ lr7) * 16);
        }
#pragma unroll
        for (int ni = 0; ni < 4; ++ni) {
            int n = ni * 16 + lr;
#pragma unroll
            for (int ks = 0; ks < 2; ++ks)
                bf[ni][ks] = *reinterpret_cast<const short8*>(bufB + n * 128 + ((ks * 4 + lg) ^ lr7) * 16);
        }
        __builtin_amdgcn_s_setprio(1);
#pragma unroll
        for (int mi = 0; mi < 2; ++mi)
#pragma unroll
            for (int ni = 0; ni < 4; ++ni) {
                acc[mi][ni] = __builtin_amdgcn_mfma_f32_16x16x32_bf16(af[mi][0], bf[ni][0], acc[mi][ni], 0, 0, 0);
                acc[mi][ni] = __builtin_amdgcn_mfma_f32_16x16x32_bf16(af[mi][1], bf[ni][1], acc[mi][ni], 0, 0, 0);
            }
        __builtin_amdgcn_s_setprio(0);
        __syncthreads();
    }
#undef STAGE_O

#pragma unroll
    for (int ni = 0; ni < 4; ++ni) {
        float bv = bias[n0 + ni * 16 + lr];
#pragma unroll
        for (int mi = 0; mi < 2; ++mi)
#pragma unroll
            for (int r = 0; r < 4; ++r) {
                int row = row0 + w * 32 + mi * 16 + lg * 4 + r;
                Y[(size_t)row * DH + n0 + ni * 16 + lr] = acc[mi][ni][r] + bv;
            }
    }
}

extern "C" void kernel_launch(void* const* d_in, const int* in_sizes, int n_in,
                              void* d_out, int out_size, void* d_ws, size_t ws_size,
                              hipStream_t stream) {
    const float* v   = (const float*)d_in[0];
    const float* k   = (const float*)d_in[1];
    const float* q   = (const float*)d_in[2];
    const int*  mask = (const int*)d_in[3];
    const float* w_v = (const float*)d_in[4];
    const float* w_k = (const float*)d_in[5];
    const float* w_q = (const float*)d_in[6];
    const float* w_o = (const float*)d_in[7];
    const float* b_o = (const float*)d_in[8];
    float* out = (float*)d_out;

    char* ws = (char*)d_ws;
    unsigned short* Qh   = (unsigned short*)(ws);                // 12.58 MB each
    unsigned short* Khc  = (unsigned short*)(ws + 12582912);     // compacted K (direct from proj3)
    unsigned short* AT   = (unsigned short*)(ws + 25165824);
    unsigned short* VhTc = (unsigned short*)(ws + 37748736);     // compacted V^T (direct from proj3)
    unsigned short* WtV  = (unsigned short*)(ws + 50331648);
    unsigned short* WtK  = WtV + 589824;
    unsigned short* WtQ  = WtK + 589824;
    unsigned short* WtO  = WtQ + 589824;
    float* biasC = (float*)(ws + 55050240);                      // 2 x 4352 f32
    int*   idxA  = (int*)(ws + 55085056);                        // 2 x 4096 int
    int*   nktA  = (int*)(ws + 55117824);                        // 4 int: nkt[2], total[2]

    wtrans4<<<dim3(144, 5), 256, 0, stream>>>(w_v, w_k, w_q, w_o, WtV, WtK, WtQ, WtO,
                                              mask, idxA, biasC, nktA);
    proj3<<<dim3(64, 18), 256, 0, stream>>>(v, k, q, WtV, WtK, WtQ, VhTc, Khc, Qh, idxA, nktA);
    attn_kernel<<<768, 256, 0, stream>>>(Qh, Khc, VhTc, biasC, nktA, AT);
    proj_out<<<dim3(64, 12), 256, 0, stream>>>(AT, WtO, b_o, out);
}

// Round 20
// 131.531 us; speedup vs baseline: 2.7364x; 2.7364x over previous
//
#include <hip/hip_runtime.h>
#include <hip/hip_bf16.h>

#define SLEN 4096
#define DH 768
#define NHEAD 12
#define DA 64

using short8 = __attribute__((ext_vector_type(8))) short;
using f32x4  = __attribute__((ext_vector_type(4))) float;
typedef unsigned uv2 __attribute__((ext_vector_type(2)));

static __device__ __forceinline__ unsigned short f2b(float f) {
    union { __hip_bfloat16 h; unsigned short u; } c;
    c.h = __float2bfloat16(f);
    return c.u;
}

static __device__ __forceinline__ unsigned pkbf(float a, float b) {
    __hip_bfloat162 h = __float22bfloat162_rn(float2{a, b});
    union { __hip_bfloat162 h; unsigned u; } c; c.h = h; return c.u;
}

// native 2^x — single v_exp_f32, no libcall fallback
static __device__ __forceinline__ float fexp2(float x) {
    float r; asm("v_exp_f32 %0, %1" : "=v"(r) : "v"(x)); return r;
}

// {a,b} -> a'={a.lo,b.lo}, b'={a.hi,b.hi}  (swap across lane^32)
static __device__ __forceinline__ void swap32(unsigned& a, unsigned& b, int g1) {
#if __has_builtin(__builtin_amdgcn_permlane32_swap)
    uv2 r = __builtin_amdgcn_permlane32_swap(a, b, false, false);
    a = r.x; b = r.y;
#else
    unsigned own = g1 ? b : a, send = g1 ? a : b;
    unsigned recv = __shfl_xor(send, 32);
    unsigned nlo = g1 ? recv : own;
    unsigned nhi = g1 ? own : recv;
    a = nlo; b = nhi;
#endif
}

// {a,b} -> a'={a.q0,b.q0,a.q2,b.q2}, b'={a.q1,b.q1,a.q3,b.q3}  (swap across lane^16)
static __device__ __forceinline__ void swap16(unsigned& a, unsigned& b, int g0) {
#if __has_builtin(__builtin_amdgcn_permlane16_swap)
    uv2 r = __builtin_amdgcn_permlane16_swap(a, b, false, false);
    a = r.x; b = r.y;
#else
    unsigned own = g0 ? b : a, send = g0 ? a : b;
    unsigned recv = __shfl_xor(send, 16);
    unsigned nlo = g0 ? recv : own;
    unsigned nhi = g0 ? own : recv;
    a = nlo; b = nhi;
#endif
}

#define GLD_LDS16(gp, lp) __builtin_amdgcn_global_load_lds( \
    (const __attribute__((address_space(1))) unsigned int*)(gp), \
    (__attribute__((address_space(3))) unsigned int*)(lp), 16, 0, 0)

#define CSCALE 0.18033688011f   // 0.125 * log2(e)
#define BIASSTRIDE 4352

// ------- merged: 4x weight transpose+cvt (z<4), mask compaction scan (z==4, blocks 0..1) -------
__global__ __launch_bounds__(256) void wtrans4(const float* __restrict__ w_v, const float* __restrict__ w_k,
                                               const float* __restrict__ w_q, const float* __restrict__ w_o,
                                               unsigned short* __restrict__ WtV, unsigned short* __restrict__ WtK,
                                               unsigned short* __restrict__ WtQ, unsigned short* __restrict__ WtO,
                                               const int* __restrict__ mask, int* __restrict__ idx,
                                               float* __restrict__ biasC, int* __restrict__ nktArr) {
    const int z = blockIdx.y;
    const int t = threadIdx.x;
    if (z == 4) {
        if (blockIdx.x >= 2) return;
        __shared__ int psum[256];
        const int b = blockIdx.x;
        const int s0 = t * 16;
        const int* mb = mask + b * SLEN;
        int keep[16]; int cnt = 0;
#pragma unroll
        for (int j = 0; j < 16; ++j) { keep[j] = (mb[s0 + j] == 0); cnt += keep[j]; }
        psum[t] = cnt;
        __syncthreads();
        for (int off = 1; off < 256; off <<= 1) {
            int v = psum[t];
            int u = (t >= off) ? psum[t - off] : 0;
            __syncthreads();
            psum[t] = v + u;
            __syncthreads();
        }
        int excl = psum[t] - cnt;
        int total = psum[255];
        int* ib = idx + b * SLEN;
#pragma unroll
        for (int j = 0; j < 16; ++j)
            if (keep[j]) ib[excl++] = s0 + j;
        for (int j = total + t; j < SLEN; j += 256) ib[j] = 0;
        int nkt = (total + 63) >> 6;
        if (nkt < 2) nkt = 2;
        if (t == 0) { nktArr[b] = nkt; nktArr[2 + b] = total; }
        float* bb = biasC + b * BIASSTRIDE;
        for (int j = t; j < BIASSTRIDE; j += 256) bb[j] = (j < total) ? 0.f : -1.442695041e9f;
        return;
    }
    const float* W = (z == 0) ? w_v : (z == 1) ? w_k : (z == 2) ? w_q : w_o;
    unsigned short* Wt = (z == 0) ? WtV : (z == 1) ? WtK : (z == 2) ? WtQ : WtO;
    __shared__ float tile[64][65];
    const int tk = blockIdx.x / 12, tn = blockIdx.x % 12;
    const int k0 = tk * 64, n0 = tn * 64;
#pragma unroll
    for (int i = 0; i < 4; ++i) {
        int uid = t + 256 * i;
        int r = uid >> 4, c = (uid & 15) * 4;
        float4 v4 = *reinterpret_cast<const float4*>(W + (size_t)(k0 + r) * DH + n0 + c);
        tile[r][c] = v4.x; tile[r][c + 1] = v4.y; tile[r][c + 2] = v4.z; tile[r][c + 3] = v4.w;
    }
    __syncthreads();
#pragma unroll
    for (int i = 0; i < 2; ++i) {
        int uid = t + 256 * i;
        int n = uid >> 3, c = (uid & 7) * 8;
        union { unsigned short us[8]; uint4 u; } pk;
#pragma unroll
        for (int j = 0; j < 8; ++j) pk.us[j] = f2b(tile[c + j][n]);
        *reinterpret_cast<uint4*>(Wt + (size_t)(n0 + n) * DH + k0 + c) = pk.u;
    }
}

// ---- fused QKV projection + compaction, m97 geometry: BM=128, BN=128, BK=32, ring-2 ----
__global__ __launch_bounds__(256, 3) void proj3(const float* __restrict__ vin, const float* __restrict__ kin,
                                                const float* __restrict__ qin,
                                                const unsigned short* __restrict__ WtV,
                                                const unsigned short* __restrict__ WtK,
                                                const unsigned short* __restrict__ WtQ,
                                                unsigned short* __restrict__ VhTc,
                                                unsigned short* __restrict__ Khc,
                                                unsigned short* __restrict__ Qh,
                                                const int* __restrict__ idx,
                                                const int* __restrict__ nktArr) {
    __shared__ __align__(16) char smem[49152];
    const int t = threadIdx.x;
    const int w = t >> 6, lane = t & 63, lr = lane & 15, lg = lane >> 4;
    const int zz = blockIdx.y;
    const int z = zz / 6, panel = zz % 6;
    const float* X = (z == 0) ? vin : (z == 1) ? kin : qin;
    const unsigned short* Wt = (z == 0) ? WtV : (z == 1) ? WtK : WtQ;
    const int b = blockIdx.x >> 5;
    const int r128 = (blockIdx.x & 31) * 128;
    const bool gather = (z != 2);
    if (gather && r128 >= nktArr[b] * 64) return;
    const int n0 = panel * 128;

    const float* ap[4];
#pragma unroll
    for (int g = 0; g < 4; ++g) {
        int row = w * 32 + g * 8 + (lane >> 3);
        int grow = b * SLEN + (gather ? idx[b * SLEN + r128 + row] : (r128 + row));
        int cj = (lane & 7) ^ (row & 7);
        ap[g] = X + (size_t)grow * DH + cj * 4;
    }
    const unsigned short* bp2[2];
#pragma unroll
    for (int g = 0; g < 2; ++g) {
        int n = w * 32 + g * 16 + (lane >> 2);
        int cj = (lane & 3) ^ (n & 3);
        bp2[g] = Wt + (size_t)(n0 + n) * DH + cj * 8;
    }

    const int arow = w * 32 + lr;
    const int lr7 = lr & 7, lr3 = lr & 3;

    f32x4 acc[2][8] = {};

#define STAGE(PAR) do {                                                              \
        char* ab_ = smem + (PAR) * 16384 + w * 4096;                                 \
        char* bb_ = smem + 32768 + (PAR) * 8192 + w * 2048;                          \
        GLD_LDS16(ap[0], ab_);         GLD_LDS16(ap[1], ab_ + 1024);                 \
        GLD_LDS16(ap[2], ab_ + 2048);  GLD_LDS16(ap[3], ab_ + 3072);                 \
        GLD_LDS16(bp2[0], bb_);        GLD_LDS16(bp2[1], bb_ + 1024);                \
        ap[0] += 32; ap[1] += 32; ap[2] += 32; ap[3] += 32;                          \
        bp2[0] += 32; bp2[1] += 32;                                                  \
    } while (0)

    STAGE(0);
    __syncthreads();

    for (int kt = 0; kt < 24; ++kt) {
        const int par = kt & 1;
        if (kt < 23) STAGE(par ^ 1);
        const char* bufA = smem + par * 16384;
        const char* bufB = smem + 32768 + par * 8192;
        short8 af[2];
#pragma unroll
        for (int mi = 0; mi < 2; ++mi) {
            int r = arow + mi * 16;
            f32x4 alo = *reinterpret_cast<const f32x4*>(bufA + r * 128 + ((2 * lg) ^ lr7) * 16);
            f32x4 ahi = *reinterpret_cast<const f32x4*>(bufA + r * 128 + ((2 * lg + 1) ^ lr7) * 16);
            union { unsigned u[4]; short8 s; } pk;
            pk.u[0] = pkbf(alo[0], alo[1]);
            pk.u[1] = pkbf(alo[2], alo[3]);
            pk.u[2] = pkbf(ahi[0], ahi[1]);
            pk.u[3] = pkbf(ahi[2], ahi[3]);
            af[mi] = pk.s;
        }
        __builtin_amdgcn_s_setprio(1);
#pragma unroll
        for (int ni = 0; ni < 8; ++ni) {
            int n = ni * 16 + lr;
            short8 bf = *reinterpret_cast<const short8*>(bufB + n * 64 + (lg ^ lr3) * 16);
            acc[0][ni] = __builtin_amdgcn_mfma_f32_16x16x32_bf16(af[0], bf, acc[0][ni], 0, 0, 0);
            acc[1][ni] = __builtin_amdgcn_mfma_f32_16x16x32_bf16(af[1], bf, acc[1][ni], 0, 0, 0);
        }
        __builtin_amdgcn_s_setprio(0);
        __syncthreads();
    }
#undef STAGE

    if (z == 0) {
        unsigned short (*tile)[136] = reinterpret_cast<unsigned short(*)[136]>(smem);
#pragma unroll
        for (int mi = 0; mi < 2; ++mi)
#pragma unroll
            for (int ni = 0; ni < 8; ++ni) {
                int n = ni * 16 + lr;
                int j = w * 32 + mi * 16 + lg * 4;
                *reinterpret_cast<unsigned*>(&tile[n][j])     = pkbf(acc[mi][ni][0], acc[mi][ni][1]);
                *reinterpret_cast<unsigned*>(&tile[n][j + 2]) = pkbf(acc[mi][ni][2], acc[mi][ni][3]);
            }
        __syncthreads();
        int n = t >> 1, jc = (t & 1) * 64;
        unsigned short* dst = VhTc +
            ((size_t)(b * NHEAD + 2 * panel + (n >> 6)) * DA + (n & 63)) * SLEN + r128 + jc;
#pragma unroll
        for (int c = 0; c < 8; ++c)
            *reinterpret_cast<uint4*>(dst + c * 8) = *reinterpret_cast<const uint4*>(&tile[n][jc + c * 8]);
    } else {
        unsigned short* Y = (z == 1) ? Khc : Qh;
        const float scale = (z == 2) ? CSCALE : 1.0f;
#pragma unroll
        for (int mi = 0; mi < 2; ++mi)
#pragma unroll
            for (int ni = 0; ni < 8; ++ni) {
                int n = n0 + ni * 16 + lr;
                int h = n >> 6, d = n & 63;
#pragma unroll
                for (int r = 0; r < 4; ++r) {
                    int s = r128 + w * 32 + mi * 16 + lg * 4 + r;
                    Y[(size_t)((b * NHEAD + h) * SLEN + s) * DA + d] = f2b(acc[mi][ni][r] * scale);
                }
            }
    }
}

// ---------------- flash attention: QBLK=128, ring-3 LDS (static offsets), fixed-m, compacted keys ----
__global__ __launch_bounds__(256, 3) void attn_kernel(const unsigned short* __restrict__ Qh,
                                                      const unsigned short* __restrict__ Kh,
                                                      const unsigned short* __restrict__ VhT,
                                                      const float* __restrict__ biasC,
                                                      const int* __restrict__ nktArr,
                                                      unsigned short* __restrict__ AT) {
    __shared__ __align__(16) char smem[49152];   // 3 x (K 8KB + V 8KB)
    const int t = threadIdx.x;
    const int w = t >> 6, lane = t & 63, lr = lane & 15, lg = lane >> 4;
    const int g0 = (lane >> 4) & 1, g1 = (lane >> 5) & 1;
    const int lr7 = lr & 7;

    const int i = blockIdx.x;          // 0..767
    const int bh = (i & 7) * 3 + ((i >> 3) >> 5);
    const int qb = (i >> 3) & 31;
    const int b = bh / NHEAD;
    const int q0 = qb * 128;
    const size_t base = (size_t)bh * SLEN * DA;
    const int wq0 = q0 + w * 32;
    const int nkt = nktArr[b];
    const int padStart = nktArr[2 + b] >> 6;   // first tile index containing pad keys

    short8 qf[2][2];
#pragma unroll
    for (int mi = 0; mi < 2; ++mi)
#pragma unroll
        for (int ks = 0; ks < 2; ++ks)
            qf[mi][ks] = *reinterpret_cast<const short8*>(
                Qh + base + (size_t)(wq0 + mi * 16 + lr) * DA + ks * 32 + lg * 8);

    const int uid0 = (w << 6) | lane;
    const int r0 = uid0 >> 3;
    const int sc0 = ((uid0 & 7) ^ (r0 & 7)) * 8;
    const unsigned short* kp = Kh + base + (size_t)r0 * DA + sc0;
    const unsigned short* vp = VhT + ((size_t)bh * DA + r0) * SLEN + sc0;
    const float* biasB = biasC + b * BIASSTRIDE + lg * 4;

    const int a0 = lr * 128 + ((lg) ^ lr7) * 16;
    const int a1 = lr * 128 + ((4 + lg) ^ lr7) * 16;

    f32x4 st[2][4];
    f32x4 oacc[2][4] = {};
    f32x4 oacc_l[2] = {};
    f32x4 bias_c[4] = {};              // zero for all full tiles
    short8 pa[2][2];
    union { unsigned u[4]; short8 s; } ones;
    ones.u[0] = 0x3F803F80u; ones.u[1] = 0x3F803F80u; ones.u[2] = 0x3F803F80u; ones.u[3] = 0x3F803F80u;

#define STAGE(CB) do {                                                   \
        GLD_LDS16(kp,              smem + (CB) + w * 1024);              \
        GLD_LDS16(kp + 2048,       smem + (CB) + (4 + w) * 1024);        \
        GLD_LDS16(vp,              smem + (CB) + 8192 + w * 1024);       \
        GLD_LDS16(vp + 32 * SLEN,  smem + (CB) + 8192 + (4 + w) * 1024); \
        kp += 64 * DA; vp += 64;                                         \
    } while (0)

#define BIASCOND(TT) do {                                                        \
        if ((TT) >= padStart) {                                                  \
            const float* bpp_ = biasB + (TT) * 64;                               \
            _Pragma("unroll") for (int ni = 0; ni < 4; ++ni)                     \
                bias_c[ni] = *reinterpret_cast<const f32x4*>(bpp_ + ni * 16);    \
        }                                                                        \
    } while (0)

#define QKT(NB) do {                                                                           \
        _Pragma("unroll") for (int ni = 0; ni < 4; ++ni) {                                     \
            short8 kf0 = *reinterpret_cast<const short8*>(smem + (NB) + ni * 2048 + a0);       \
            short8 kf1 = *reinterpret_cast<const short8*>(smem + (NB) + ni * 2048 + a1);       \
            st[0][ni] = __builtin_amdgcn_mfma_f32_16x16x32_bf16(kf1, qf[0][1],                 \
                        __builtin_amdgcn_mfma_f32_16x16x32_bf16(kf0, qf[0][0], bias_c[ni], 0, 0, 0), 0, 0, 0); \
            st[1][ni] = __builtin_amdgcn_mfma_f32_16x16x32_bf16(kf1, qf[1][1],                 \
                        __builtin_amdgcn_mfma_f32_16x16x32_bf16(kf0, qf[1][0], bias_c[ni], 0, 0, 0), 0, 0, 0); \
        }                                                                                      \
    } while (0)

#define PV(CB) do {                                                                                  \
        _Pragma("unroll") for (int ni = 0; ni < 4; ++ni) {                                           \
            short8 vf0 = *reinterpret_cast<const short8*>(smem + (CB) + 8192 + ni * 2048 + a0);      \
            short8 vf1 = *reinterpret_cast<const short8*>(smem + (CB) + 8192 + ni * 2048 + a1);      \
            oacc[0][ni] = __builtin_amdgcn_mfma_f32_16x16x32_bf16(vf0, pa[0][0], oacc[0][ni], 0, 0, 0); \
            oacc[0][ni] = __builtin_amdgcn_mfma_f32_16x16x32_bf16(vf1, pa[0][1], oacc[0][ni], 0, 0, 0); \
            oacc[1][ni] = __builtin_amdgcn_mfma_f32_16x16x32_bf16(vf0, pa[1][0], oacc[1][ni], 0, 0, 0); \
            oacc[1][ni] = __builtin_amdgcn_mfma_f32_16x16x32_bf16(vf1, pa[1][1], oacc[1][ni], 0, 0, 0); \
        }                                                                                            \
        oacc_l[0] = __builtin_amdgcn_mfma_f32_16x16x32_bf16(ones.s, pa[0][0], oacc_l[0], 0, 0, 0);   \
        oacc_l[0] = __builtin_amdgcn_mfma_f32_16x16x32_bf16(ones.s, pa[0][1], oacc_l[0], 0, 0, 0);   \
        oacc_l[1] = __builtin_amdgcn_mfma_f32_16x16x32_bf16(ones.s, pa[1][0], oacc_l[1], 0, 0, 0);   \
        oacc_l[1] = __builtin_amdgcn_mfma_f32_16x16x32_bf16(ones.s, pa[1][1], oacc_l[1], 0, 0, 0);   \
    } while (0)

#define SOFTMAX do {                                                                               \
        _Pragma("unroll") for (int mi = 0; mi < 2; ++mi) {                                         \
            unsigned D[8];                                                                         \
            _Pragma("unroll") for (int ni = 0; ni < 4; ++ni) {                                     \
                float p0 = fexp2(st[mi][ni][0]);                                                   \
                float p1 = fexp2(st[mi][ni][1]);                                                   \
                float p2 = fexp2(st[mi][ni][2]);                                                   \
                float p3 = fexp2(st[mi][ni][3]);                                                   \
                D[ni * 2] = pkbf(p0, p1);                                                          \
                D[ni * 2 + 1] = pkbf(p2, p3);                                                      \
            }                                                                                      \
            swap32(D[0], D[2], g1); swap32(D[1], D[3], g1);                                        \
            swap32(D[4], D[6], g1); swap32(D[5], D[7], g1);                                        \
            swap16(D[0], D[2], g0); swap16(D[1], D[3], g0);                                        \
            swap16(D[4], D[6], g0); swap16(D[5], D[7], g0);                                        \
            union { unsigned u[4]; short8 s; } c0, c1;                                             \
            c0.u[0] = D[0]; c0.u[1] = D[1]; c0.u[2] = D[2]; c0.u[3] = D[3];                        \
            c1.u[0] = D[4]; c1.u[1] = D[5]; c1.u[2] = D[6]; c1.u[3] = D[7];                        \
            pa[mi][0] = c0.s; pa[mi][1] = c1.s;                                                    \
        }                                                                                          \
    } while (0)

#define BODY(KT, CB, NB, NNB) do {                                       \
        SOFTMAX;                                                         \
        __syncthreads();                                                 \
        if ((KT) < nkt - 2) STAGE(NNB);                                  \
        BIASCOND((KT) + 1);                                              \
        __builtin_amdgcn_s_setprio(1);                                   \
        QKT(NB);                                                         \
        PV(CB);                                                          \
        __builtin_amdgcn_s_setprio(0);                                   \
    } while (0)

    // prologue: stage tiles 0,1; bias(0) (only if padded); QKT(0)
    STAGE(0);
    __syncthreads();
    STAGE(16384);
    BIASCOND(0);
    __builtin_amdgcn_s_setprio(1);
    QKT(0);
    __builtin_amdgcn_s_setprio(0);

    int kt = 0;
    while (kt + 3 <= nkt - 1) {
        BODY(kt,     0,     16384, 32768);
        BODY(kt + 1, 16384, 32768, 0);
        BODY(kt + 2, 32768, 0,     16384);
        kt += 3;
    }
    const int rem = (nkt - 1) - kt;    // 0..2 remaining loop-bodies
    if (rem >= 1) BODY(kt,     0,     16384, 32768);
    if (rem >= 2) BODY(kt + 1, 16384, 32768, 0);
    // final tile (nkt-1), lives in buffer ((nkt-1) % 3)
    SOFTMAX;
    {
        const int cbF = ((nkt - 1) % 3) * 16384;
        __builtin_amdgcn_s_setprio(1);
        PV(cbF);
        __builtin_amdgcn_s_setprio(0);
    }

#undef BODY
#undef SOFTMAX
#undef PV
#undef QKT
#undef BIASCOND
#undef STAGE

    {
        __syncthreads();
        float inv[2];
        inv[0] = 1.0f / oacc_l[0][0];
        inv[1] = 1.0f / oacc_l[1][0];
        unsigned* Obw = reinterpret_cast<unsigned*>(smem) + w * (32 * 36);
#pragma unroll
        for (int mi = 0; mi < 2; ++mi)
#pragma unroll
            for (int ni = 0; ni < 4; ++ni) {
                uint2 pr;
                pr.x = pkbf(oacc[mi][ni][0] * inv[mi], oacc[mi][ni][1] * inv[mi]);
                pr.y = pkbf(oacc[mi][ni][2] * inv[mi], oacc[mi][ni][3] * inv[mi]);
                *reinterpret_cast<uint2*>(&Obw[(mi * 16 + lr) * 36 + ni * 8 + lg * 2]) = pr;
            }
        __syncthreads();
        int row = lane >> 1, half = lane & 1;
        int qg = q0 + w * 32 + row;
        unsigned short* dst = AT + (size_t)(b * SLEN + qg) * DH + (bh % NHEAD) * DA + half * 32;
#pragma unroll
        for (int c = 0; c < 4; ++c) {
            uint4 v = *reinterpret_cast<const uint4*>(&Obw[row * 36 + half * 16 + c * 4]);
            *reinterpret_cast<uint4*>(dst + c * 8) = v;
        }
    }
}

// ---- output projection, m97 geometry: BM=128, BN=64, BK=64, ring-2, 1 barrier/K-step ----
__global__ __launch_bounds__(256, 3) void proj_out(const unsigned short* __restrict__ X,
                                                   const unsigned short* __restrict__ Wt,
                                                   const float* __restrict__ bias,
                                                   float* __restrict__ Y) {
    __shared__ __align__(16) char smem[49152];
    const int t = threadIdx.x;
    const int w = t >> 6, lane = t & 63, lr = lane & 15, lg = lane >> 4;
    const int row0 = blockIdx.x * 128;
    const int n0 = blockIdx.y * 64;
    const int lr7 = lr & 7;

    const unsigned short* ap[4];
#pragma unroll
    for (int g = 0; g < 4; ++g) {
        int row = w * 32 + g * 8 + (lane >> 3);
        int cj = (lane & 7) ^ (row & 7);
        ap[g] = X + (size_t)(row0 + row) * DH + cj * 8;
    }
    const unsigned short* bp2[2];
#pragma unroll
    for (int g = 0; g < 2; ++g) {
        int n = w * 16 + g * 8 + (lane >> 3);
        int cj = (lane & 7) ^ (n & 7);
        bp2[g] = Wt + (size_t)(n0 + n) * DH + cj * 8;
    }

    f32x4 acc[2][4] = {};

#define STAGE_O(PAR) do {                                                            \
        char* ab_ = smem + (PAR) * 16384 + w * 4096;                                 \
        char* bb_ = smem + 32768 + (PAR) * 8192 + w * 2048;                          \
        GLD_LDS16(ap[0], ab_);         GLD_LDS16(ap[1], ab_ + 1024);                 \
        GLD_LDS16(ap[2], ab_ + 2048);  GLD_LDS16(ap[3], ab_ + 3072);                 \
        GLD_LDS16(bp2[0], bb_);        GLD_LDS16(bp2[1], bb_ + 1024);                \
        ap[0] += 64; ap[1] += 64; ap[2] += 64; ap[3] += 64;                          \
        bp2[0] += 64; bp2[1] += 64;                                                  \
    } while (0)

    STAGE_O(0);
    __syncthreads();

    for (int kt = 0; kt < 12; ++kt) {
        const int par = kt & 1;
        if (kt < 11) STAGE_O(par ^ 1);
        const char* bufA = smem + par * 16384;
        const char* bufB = smem + 32768 + par * 8192;
        short8 af[2][2], bf[4][2];
#pragma unroll
        for (int mi = 0; mi < 2; ++mi) {
            int r = w * 32 + mi * 16 + lr;
#pragma unroll
            for (int ks = 0; ks < 2; ++ks)
                af[mi][ks] = *reinterpret_cast<const short8*>(bufA + r * 128 + ((ks * 4 + lg) ^ lr7) * 16);
        }
#pragma unroll
        for (int ni = 0; ni < 4; ++ni) {
            int n = ni * 16 + lr;
#pragma unroll
            for (int ks = 0; ks < 2; ++ks)
                bf[ni][ks] = *reinterpret_cast<const short8*>(bufB + n * 128 + ((ks * 4 + lg) ^ lr7) * 16);
        }
        __builtin_amdgcn_s_setprio(1);
#pragma unroll
        for (int mi = 0; mi < 2; ++mi)
#pragma unroll
            for (int ni = 0; ni < 4; ++ni) {
                acc[mi][ni] = __builtin_amdgcn_mfma_f32_16x16x32_bf16(af[mi][0], bf[ni][0], acc[mi][ni], 0, 0, 0);
                acc[mi][ni] = __builtin_amdgcn_mfma_f32_16x16x32_bf16(af[mi][1], bf[ni][1], acc[mi][ni], 0, 0, 0);
            }
        __builtin_amdgcn_s_setprio(0);
        __syncthreads();
    }
#undef STAGE_O

#pragma unroll
    for (int ni = 0; ni < 4; ++ni) {
        float bv = bias[n0 + ni * 16 + lr];
#pragma unroll
        for (int mi = 0; mi < 2; ++mi)
#pragma unroll
            for (int r = 0; r < 4; ++r) {
                int row = row0 + w * 32 + mi * 16 + lg * 4 + r;
                Y[(size_t)row * DH + n0 + ni * 16 + lr] = acc[mi][ni][r] + bv;
            }
    }
}

extern "C" void kernel_launch(void* const* d_in, const int* in_sizes, int n_in,
                              void* d_out, int out_size, void* d_ws, size_t ws_size,
                              hipStream_t stream) {
    const float* v   = (const float*)d_in[0];
    const float* k   = (const float*)d_in[1];
    const float* q   = (const float*)d_in[2];
    const int*  mask = (const int*)d_in[3];
    const float* w_v = (const float*)d_in[4];
    const float* w_k = (const float*)d_in[5];
    const float* w_q = (const float*)d_in[6];
    const float* w_o = (const float*)d_in[7];
    const float* b_o = (const float*)d_in[8];
    float* out = (float*)d_out;

    char* ws = (char*)d_ws;
    unsigned short* Qh   = (unsigned short*)(ws);                // 12.58 MB each
    unsigned short* Khc  = (unsigned short*)(ws + 12582912);     // compacted K (direct from proj3)
    unsigned short* AT   = (unsigned short*)(ws + 25165824);
    unsigned short* VhTc = (unsigned short*)(ws + 37748736);     // compacted V^T (direct from proj3)
    unsigned short* WtV  = (unsigned short*)(ws + 50331648);
    unsigned short* WtK  = WtV + 589824;
    unsigned short* WtQ  = WtK + 589824;
    unsigned short* WtO  = WtQ + 589824;
    float* biasC = (float*)(ws + 55050240);                      // 2 x 4352 f32
    int*   idxA  = (int*)(ws + 55085056);                        // 2 x 4096 int
    int*   nktA  = (int*)(ws + 55117824);                        // 4 int: nkt[2], total[2]

    wtrans4<<<dim3(144, 5), 256, 0, stream>>>(w_v, w_k, w_q, w_o, WtV, WtK, WtQ, WtO,
                                              mask, idxA, biasC, nktA);
    proj3<<<dim3(64, 18), 256, 0, stream>>>(v, k, q, WtV, WtK, WtQ, VhTc, Khc, Qh, idxA, nktA);
    attn_kernel<<<768, 256, 0, stream>>>(Qh, Khc, VhTc, biasC, nktA, AT);
    proj_out<<<dim3(64, 12), 256, 0, stream>>>(AT, WtO, b_o, out);
}